// Round 1
// baseline (177.356 us; speedup 1.0000x reference)
//
#include <hip/hip_runtime.h>
#include <math.h>

#define NCAT  5
#define BATCH 64
#define ELEMS 196608   // C*H*W = 3*256*256
#define EPSV  1e-6f

// acc layout (floats in d_ws): [0..4] = cat_scaled_sum, [5..9] = cat_abs_sum,
// [10..14] = acc_un (sum over chw of per-cat un sums)
__global__ __launch_bounds__(256) void accum_kernel(
    const float* __restrict__ restored,
    const float* __restrict__ clean,
    const int*   __restrict__ de_id,
    const float* __restrict__ un,
    float*       __restrict__ acc)
{
    __shared__ int   sh_de[BATCH];
    __shared__ float sred[4][3 * NCAT];

    const int tid = threadIdx.x;
    if (tid < BATCH) sh_de[tid] = de_id[tid];
    __syncthreads();

    // per-thread category counts (identical across threads; cheap)
    int cnt[NCAT] = {0, 0, 0, 0, 0};
    #pragma unroll 8
    for (int b = 0; b < BATCH; ++b) {
        int k = sh_de[b];
        #pragma unroll
        for (int j = 0; j < NCAT; ++j) cnt[j] += (k == j) ? 1 : 0;
    }

    const int p = blockIdx.x * 256 + tid;   // position index, < ELEMS
    float un_s[NCAT] = {0.f, 0.f, 0.f, 0.f, 0.f};
    float ad_s[NCAT] = {0.f, 0.f, 0.f, 0.f, 0.f};

    const float* rp = restored + p;
    const float* cp = clean + p;
    const float* up = un + p;

    #pragma unroll 4
    for (int b = 0; b < BATCH; ++b) {
        const long off = (long)b * ELEMS;
        float u  = up[off];
        float ad = fabsf(cp[off] - rp[off]);
        int   k  = sh_de[b];
        #pragma unroll
        for (int j = 0; j < NCAT; ++j) {
            float m = (k == j) ? 1.0f : 0.0f;
            un_s[j] = fmaf(m, u,  un_s[j]);
            ad_s[j] = fmaf(m, ad, ad_s[j]);
        }
    }

    // per-position contributions to the 15 global accumulators
    float vals[3 * NCAT];
    #pragma unroll
    for (int j = 0; j < NCAT; ++j) {
        float safe   = (float)(cnt[j] > 0 ? cnt[j] : 1);
        float un_map = un_s[j] / safe + EPSV;     // matches ref per-position un_map
        vals[j]            = ad_s[j] / un_map;    // scaled L1 contribution
        vals[NCAT + j]     = ad_s[j];             // raw abs sum
        vals[2 * NCAT + j] = un_s[j];             // raw un sum
    }

    // wave (64-lane) butterfly reduction
    #pragma unroll
    for (int i = 0; i < 3 * NCAT; ++i) {
        float v = vals[i];
        #pragma unroll
        for (int off = 32; off >= 1; off >>= 1)
            v += __shfl_down(v, off, 64);
        vals[i] = v;
    }

    const int wave = tid >> 6;
    const int lane = tid & 63;
    if (lane == 0) {
        #pragma unroll
        for (int i = 0; i < 3 * NCAT; ++i) sred[wave][i] = vals[i];
    }
    __syncthreads();

    if (tid < 3 * NCAT) {
        float v = sred[0][tid] + sred[1][tid] + sred[2][tid] + sred[3][tid];
        atomicAdd(&acc[tid], v);
    }
}

// Tiny epilogue: compute the 21 outputs (total, cat_losses[5], old_loss[5],
// bn[5], unc_l1[5]) replicating the reference's cumulative-list semantics.
__global__ void epilogue_kernel(const int*   __restrict__ de_id,
                                const float* __restrict__ acc,
                                float*       __restrict__ out)
{
    if (threadIdx.x != 0 || blockIdx.x != 0) return;

    int cnt[NCAT] = {0, 0, 0, 0, 0};
    for (int b = 0; b < BATCH; ++b) cnt[de_id[b]]++;

    const float Ef = (float)ELEMS;
    float cum_s = 0.f;
    long  cum_c = 0;
    float total = 0.f;
    int   num   = 0;

    float cat_losses[NCAT], old_loss[NCAT], bn[NCAT], unc_l1[NCAT];

    for (int j = 0; j < NCAT; ++j) {
        cum_s += acc[j];          // cumsum of cat_scaled_sum
        cum_c += cnt[j];
        float cum_elems = (float)cum_c * Ef;
        float cum_l1    = cum_s / fmaxf(cum_elems, 1.0f);

        bool  ne   = cnt[j] > 0;
        float safe = (float)(ne ? cnt[j] : 1);

        old_loss[j]  = ne ? acc[NCAT + j] / (safe * Ef) : 0.f;
        float un_num = acc[2 * NCAT + j] / (safe * Ef) + EPSV;
        bn[j]        = ne ? 2.0f * logf(un_num) : 0.f;
        unc_l1[j]    = ne ? cum_l1 : 0.f;
        cat_losses[j] = unc_l1[j] + bn[j];
        total += cat_losses[j];
        num   += ne ? 1 : 0;
    }
    total /= (float)num;

    out[0] = total;
    for (int j = 0; j < NCAT; ++j) {
        out[1 + j]  = cat_losses[j];
        out[6 + j]  = old_loss[j];
        out[11 + j] = bn[j];
        out[16 + j] = unc_l1[j];
    }
}

extern "C" void kernel_launch(void* const* d_in, const int* in_sizes, int n_in,
                              void* d_out, int out_size, void* d_ws, size_t ws_size,
                              hipStream_t stream) {
    (void)in_sizes; (void)n_in; (void)out_size; (void)ws_size;
    const float* restored = (const float*)d_in[0];
    const float* clean    = (const float*)d_in[1];
    const int*   de_id    = (const int*)d_in[2];
    const float* un       = (const float*)d_in[3];
    float* out = (float*)d_out;
    float* acc = (float*)d_ws;

    // d_ws is poisoned 0xAA before every launch — zero the 15 accumulators.
    hipMemsetAsync(acc, 0, 3 * NCAT * sizeof(float), stream);
    accum_kernel<<<ELEMS / 256, 256, 0, stream>>>(restored, clean, de_id, un, acc);
    epilogue_kernel<<<1, 64, 0, stream>>>(de_id, acc, out);
}

// Round 2
// 176.235 us; speedup vs baseline: 1.0064x; 1.0064x over previous
//
#include <hip/hip_runtime.h>
#include <math.h>

#define NCAT  5
#define BATCH 64
#define ELEMS 196608        // C*H*W = 3*256*256
#define HALF_ELEMS 98304    // ELEMS/2, in float2 units
#define NBLK 768
#define TPB  128
#define EPSV 1e-6f

// d_ws layout: partials[15][NBLK] floats.
// rows 0..4  = per-block cat_scaled_sum, 5..9 = cat_abs_sum, 10..14 = un sums
__global__ __launch_bounds__(TPB) void accum_kernel(
    const float2* __restrict__ restored,
    const float2* __restrict__ clean,
    const int*    __restrict__ de_id,
    const float2* __restrict__ un,
    float*        __restrict__ partials)
{
    __shared__ int   sh_de[BATCH];
    __shared__ float sh_inv[NCAT];
    __shared__ float sred[TPB / 64][3 * NCAT];

    const int tid = threadIdx.x;

    // wave 0: load de_id, ballot-count categories, store 1/safe_count
    if (tid < 64) {
        int k = de_id[tid];
        sh_de[tid] = k;
        #pragma unroll
        for (int j = 0; j < NCAT; ++j) {
            unsigned long long m = __ballot(k == j);
            if (tid == j) {
                int c = __popcll(m);
                sh_inv[j] = 1.0f / (float)(c > 0 ? c : 1);
            }
        }
    }
    __syncthreads();

    float inv_safe[NCAT];
    #pragma unroll
    for (int j = 0; j < NCAT; ++j) inv_safe[j] = sh_inv[j];

    const int gid = blockIdx.x * TPB + tid;     // float2 position index
    const float2* rp = restored + gid;
    const float2* cp = clean + gid;
    const float2* up = un + gid;

    float2 un_s[NCAT], ad_s[NCAT];
    #pragma unroll
    for (int j = 0; j < NCAT; ++j) {
        un_s[j].x = un_s[j].y = 0.f;
        ad_s[j].x = ad_s[j].y = 0.f;
    }

    #pragma unroll 8
    for (int b = 0; b < BATCH; ++b) {
        const size_t off = (size_t)b * HALF_ELEMS;
        float2 u = up[off];
        float2 c = cp[off];
        float2 r = rp[off];
        float adx = fabsf(c.x - r.x);
        float ady = fabsf(c.y - r.y);
        int k = sh_de[b];
        #pragma unroll
        for (int j = 0; j < NCAT; ++j) {
            float m = (k == j) ? 1.0f : 0.0f;
            un_s[j].x = fmaf(m, u.x, un_s[j].x);
            un_s[j].y = fmaf(m, u.y, un_s[j].y);
            ad_s[j].x = fmaf(m, adx, ad_s[j].x);
            ad_s[j].y = fmaf(m, ady, ad_s[j].y);
        }
    }

    // per-thread contributions (per-position division, then pair-sum)
    float vals[3 * NCAT];
    #pragma unroll
    for (int j = 0; j < NCAT; ++j) {
        float umx = fmaf(un_s[j].x, inv_safe[j], EPSV);
        float umy = fmaf(un_s[j].y, inv_safe[j], EPSV);
        vals[j]            = ad_s[j].x / umx + ad_s[j].y / umy;
        vals[NCAT + j]     = ad_s[j].x + ad_s[j].y;
        vals[2 * NCAT + j] = un_s[j].x + un_s[j].y;
    }

    // 64-lane butterfly reduction
    #pragma unroll
    for (int i = 0; i < 3 * NCAT; ++i) {
        float v = vals[i];
        #pragma unroll
        for (int off = 32; off >= 1; off >>= 1)
            v += __shfl_down(v, off, 64);
        vals[i] = v;
    }

    const int wave = tid >> 6;
    const int lane = tid & 63;
    if (lane == 0) {
        #pragma unroll
        for (int i = 0; i < 3 * NCAT; ++i) sred[wave][i] = vals[i];
    }
    __syncthreads();

    if (tid < 3 * NCAT) {
        float v = sred[0][tid] + sred[1][tid];
        partials[tid * NBLK + blockIdx.x] = v;   // transposed: row-contiguous
    }
}

// 1 block, 256 threads: reduce [15][768] partials + final 21-output math
__global__ __launch_bounds__(256) void epilogue_kernel(
    const int*   __restrict__ de_id,
    const float* __restrict__ partials,
    float*       __restrict__ out)
{
    __shared__ int   sh_cnt[NCAT];
    __shared__ float sh_acc[3 * NCAT];

    const int tid = threadIdx.x;

    if (tid < 64) {
        int k = de_id[tid];
        #pragma unroll
        for (int j = 0; j < NCAT; ++j) {
            unsigned long long m = __ballot(k == j);
            if (tid == j) sh_cnt[j] = __popcll(m);
        }
    }

    if (tid < 240) {
        const int row    = tid >> 4;
        const int lane16 = tid & 15;
        float v = 0.f;
        #pragma unroll 4
        for (int k = 0; k < NBLK / 16; ++k)
            v += partials[row * NBLK + lane16 + (k << 4)];
        v += __shfl_down(v, 8, 16);
        v += __shfl_down(v, 4, 16);
        v += __shfl_down(v, 2, 16);
        v += __shfl_down(v, 1, 16);
        if (lane16 == 0) sh_acc[row] = v;
    }
    __syncthreads();

    if (tid == 0) {
        const float Ef = (float)ELEMS;
        float cum_s = 0.f;
        long  cum_c = 0;
        float total = 0.f;
        int   num   = 0;

        float cat_losses[NCAT], old_loss[NCAT], bn[NCAT], unc_l1[NCAT];

        for (int j = 0; j < NCAT; ++j) {
            cum_s += sh_acc[j];
            cum_c += sh_cnt[j];
            float cum_elems = (float)cum_c * Ef;
            float cum_l1    = cum_s / fmaxf(cum_elems, 1.0f);

            bool  ne   = sh_cnt[j] > 0;
            float safe = (float)(ne ? sh_cnt[j] : 1);

            old_loss[j]  = ne ? sh_acc[NCAT + j] / (safe * Ef) : 0.f;
            float un_num = sh_acc[2 * NCAT + j] / (safe * Ef) + EPSV;
            bn[j]        = ne ? 2.0f * logf(un_num) : 0.f;
            unc_l1[j]    = ne ? cum_l1 : 0.f;
            cat_losses[j] = unc_l1[j] + bn[j];
            total += cat_losses[j];
            num   += ne ? 1 : 0;
        }
        total /= (float)num;

        out[0] = total;
        for (int j = 0; j < NCAT; ++j) {
            out[1 + j]  = cat_losses[j];
            out[6 + j]  = old_loss[j];
            out[11 + j] = bn[j];
            out[16 + j] = unc_l1[j];
        }
    }
}

extern "C" void kernel_launch(void* const* d_in, const int* in_sizes, int n_in,
                              void* d_out, int out_size, void* d_ws, size_t ws_size,
                              hipStream_t stream) {
    (void)in_sizes; (void)n_in; (void)out_size; (void)ws_size;
    const float2* restored = (const float2*)d_in[0];
    const float2* clean    = (const float2*)d_in[1];
    const int*    de_id    = (const int*)d_in[2];
    const float2* un       = (const float2*)d_in[3];
    float* out      = (float*)d_out;
    float* partials = (float*)d_ws;   // [15][NBLK] — fully overwritten, no init needed

    accum_kernel<<<NBLK, TPB, 0, stream>>>(restored, clean, de_id, un, partials);
    epilogue_kernel<<<1, 256, 0, stream>>>(de_id, partials, out);
}

// Round 3
// 173.272 us; speedup vs baseline: 1.0236x; 1.0171x over previous
//
#include <hip/hip_runtime.h>
#include <math.h>

#define NCAT  5
#define BATCH 64
#define ELEMS 196608        // C*H*W = 3*256*256
#define NBLK  768
#define TPB   256           // 768*256 = 196608 threads, one float each
#define GRP   8             // batches per pipeline stage
#define EPSV  1e-6f

// d_ws layout: partials[15][NBLK] floats.
// rows 0..4 = per-block cat_scaled_sum, 5..9 = cat_abs_sum, 10..14 = un sums
__global__ __launch_bounds__(TPB) void accum_kernel(
    const float* __restrict__ restored,
    const float* __restrict__ clean,
    const int*   __restrict__ de_id,
    const float* __restrict__ un,
    float*       __restrict__ partials)
{
    __shared__ int   sh_de[BATCH];
    __shared__ float sh_inv[NCAT];
    __shared__ float sred[TPB / 64][3 * NCAT];

    const int tid = threadIdx.x;

    // wave 0: load de_id, ballot-count categories, store 1/safe_count
    if (tid < 64) {
        int k = de_id[tid];
        sh_de[tid] = k;
        #pragma unroll
        for (int j = 0; j < NCAT; ++j) {
            unsigned long long m = __ballot(k == j);
            if (tid == j) {
                int c = __popcll(m);
                sh_inv[j] = 1.0f / (float)(c > 0 ? c : 1);
            }
        }
    }
    __syncthreads();

    const int p = blockIdx.x * TPB + tid;   // scalar position index
    const float* rp = restored + p;
    const float* cp = clean + p;
    const float* up = un + p;

    float un_s[NCAT] = {0.f, 0.f, 0.f, 0.f, 0.f};
    float ad_s[NCAT] = {0.f, 0.f, 0.f, 0.f, 0.f};

    // double-buffered register pipeline: GRP batches (3*GRP dword loads) per
    // stage, next stage's loads issued before current stage's compute.
    float ub[2][GRP], cb[2][GRP], rb[2][GRP];

    #pragma unroll
    for (int i = 0; i < GRP; ++i) {
        const size_t off = (size_t)i * ELEMS;
        ub[0][i] = up[off];
        cb[0][i] = cp[off];
        rb[0][i] = rp[off];
    }

    #pragma unroll
    for (int g = 0; g < BATCH / GRP; ++g) {
        const int cur = g & 1;
        const int nxt = cur ^ 1;
        if (g < BATCH / GRP - 1) {
            #pragma unroll
            for (int i = 0; i < GRP; ++i) {
                const size_t off = (size_t)((g + 1) * GRP + i) * ELEMS;
                ub[nxt][i] = up[off];
                cb[nxt][i] = cp[off];
                rb[nxt][i] = rp[off];
            }
        }
        #pragma unroll
        for (int i = 0; i < GRP; ++i) {
            float u  = ub[cur][i];
            float ad = fabsf(cb[cur][i] - rb[cur][i]);
            int   k  = sh_de[g * GRP + i];
            #pragma unroll
            for (int j = 0; j < NCAT; ++j) {
                float m = (k == j) ? 1.0f : 0.0f;
                un_s[j] = fmaf(m, u,  un_s[j]);
                ad_s[j] = fmaf(m, ad, ad_s[j]);
            }
        }
    }

    // per-position contributions to the 15 accumulators
    float vals[3 * NCAT];
    #pragma unroll
    for (int j = 0; j < NCAT; ++j) {
        float um = fmaf(un_s[j], sh_inv[j], EPSV);   // un_map at this position
        vals[j]            = ad_s[j] / um;
        vals[NCAT + j]     = ad_s[j];
        vals[2 * NCAT + j] = un_s[j];
    }

    // 64-lane butterfly reduction
    #pragma unroll
    for (int i = 0; i < 3 * NCAT; ++i) {
        float v = vals[i];
        #pragma unroll
        for (int off = 32; off >= 1; off >>= 1)
            v += __shfl_down(v, off, 64);
        vals[i] = v;
    }

    const int wave = tid >> 6;
    const int lane = tid & 63;
    if (lane == 0) {
        #pragma unroll
        for (int i = 0; i < 3 * NCAT; ++i) sred[wave][i] = vals[i];
    }
    __syncthreads();

    if (tid < 3 * NCAT) {
        float v = sred[0][tid] + sred[1][tid] + sred[2][tid] + sred[3][tid];
        partials[tid * NBLK + blockIdx.x] = v;   // transposed: row-contiguous
    }
}

// 1 block, 256 threads: reduce [15][768] partials + final 21-output math
__global__ __launch_bounds__(256) void epilogue_kernel(
    const int*   __restrict__ de_id,
    const float* __restrict__ partials,
    float*       __restrict__ out)
{
    __shared__ int   sh_cnt[NCAT];
    __shared__ float sh_acc[3 * NCAT];

    const int tid = threadIdx.x;

    if (tid < 64) {
        int k = de_id[tid];
        #pragma unroll
        for (int j = 0; j < NCAT; ++j) {
            unsigned long long m = __ballot(k == j);
            if (tid == j) sh_cnt[j] = __popcll(m);
        }
    }

    if (tid < 240) {
        const int row    = tid >> 4;
        const int lane16 = tid & 15;
        float v = 0.f;
        #pragma unroll 4
        for (int k = 0; k < NBLK / 16; ++k)
            v += partials[row * NBLK + lane16 + (k << 4)];
        v += __shfl_down(v, 8, 16);
        v += __shfl_down(v, 4, 16);
        v += __shfl_down(v, 2, 16);
        v += __shfl_down(v, 1, 16);
        if (lane16 == 0) sh_acc[row] = v;
    }
    __syncthreads();

    if (tid == 0) {
        const float Ef = (float)ELEMS;
        float cum_s = 0.f;
        long  cum_c = 0;
        float total = 0.f;
        int   num   = 0;

        float cat_losses[NCAT], old_loss[NCAT], bn[NCAT], unc_l1[NCAT];

        for (int j = 0; j < NCAT; ++j) {
            cum_s += sh_acc[j];
            cum_c += sh_cnt[j];
            float cum_elems = (float)cum_c * Ef;
            float cum_l1    = cum_s / fmaxf(cum_elems, 1.0f);

            bool  ne   = sh_cnt[j] > 0;
            float safe = (float)(ne ? sh_cnt[j] : 1);

            old_loss[j]  = ne ? sh_acc[NCAT + j] / (safe * Ef) : 0.f;
            float un_num = sh_acc[2 * NCAT + j] / (safe * Ef) + EPSV;
            bn[j]        = ne ? 2.0f * logf(un_num) : 0.f;
            unc_l1[j]    = ne ? cum_l1 : 0.f;
            cat_losses[j] = unc_l1[j] + bn[j];
            total += cat_losses[j];
            num   += ne ? 1 : 0;
        }
        total /= (float)num;

        out[0] = total;
        for (int j = 0; j < NCAT; ++j) {
            out[1 + j]  = cat_losses[j];
            out[6 + j]  = old_loss[j];
            out[11 + j] = bn[j];
            out[16 + j] = unc_l1[j];
        }
    }
}

extern "C" void kernel_launch(void* const* d_in, const int* in_sizes, int n_in,
                              void* d_out, int out_size, void* d_ws, size_t ws_size,
                              hipStream_t stream) {
    (void)in_sizes; (void)n_in; (void)out_size; (void)ws_size;
    const float* restored = (const float*)d_in[0];
    const float* clean    = (const float*)d_in[1];
    const int*   de_id    = (const int*)d_in[2];
    const float* un       = (const float*)d_in[3];
    float* out      = (float*)d_out;
    float* partials = (float*)d_ws;   // [15][NBLK] — fully overwritten, no init needed

    accum_kernel<<<NBLK, TPB, 0, stream>>>(restored, clean, de_id, un, partials);
    epilogue_kernel<<<1, 256, 0, stream>>>(de_id, partials, out);
}